// Round 27
// baseline (226.132 us; speedup 1.0000x reference)
//
#include <hip/hip_runtime.h>
#include <hip/hip_bf16.h>
#include <hip/hip_fp16.h>
#include <math.h>

#define B_    64
#define L_    512
#define C_    321
#define PRED_ 96
#define N_    64
#define HID_  32
#define BC_   (B_*C_)   // 20544
#define SROW_ 528
#define EPS_  1e-5f
#define ALPHA_ 0.2f
#define GR_   16
#define RB_   8
#define NBLK2_ (BC_/GR_) // 1284
#define NBLKH_ (BC_/8)   // 2568
#define D64_  6.2771017353866808e-7f   // 0.8^64
#define STW_  548
#define UTW_  260

typedef __attribute__((ext_vector_type(8))) short bf16x8;
typedef __attribute__((ext_vector_type(4))) float f32x4;

__device__ __forceinline__ float gelu_f(float x){
  float ax = fabsf(x);
  float z  = ax * 0.70710678118654752440f;
  float t  = __builtin_amdgcn_rcpf(fmaf(0.3275911f, z, 1.0f));
  float poly = fmaf(fmaf(fmaf(fmaf(1.061405429f, t, -1.453152027f),
                   t, 1.421413741f), t, -0.284496736f), t, 0.254829592f) * t;
  float e  = __expf(-z*z);
  float erfp = fmaf(-poly, e, 1.0f);
  return fmaf(0.5f*ax, erfp, 0.5f*x);
}
__device__ __forceinline__ unsigned short bf16bits(float x){
  __hip_bfloat16 h = __float2bfloat16(x);
  return *(unsigned short*)&h;
}
__device__ __forceinline__ unsigned short f16bits(float x){
  __half h = __float2half(x);
  return *(unsigned short*)&h;
}
__device__ __forceinline__ float f16val(unsigned short u){
  __half h = *(__half*)&u;
  return __half2float(h);
}
__device__ __forceinline__ bf16x8 cvt8(const float* p){
  float4 a = *(const float4*)p;
  float4 b = *(const float4*)(p+4);
  bf16x8 v;
  v[0]=(short)bf16bits(a.x); v[1]=(short)bf16bits(a.y);
  v[2]=(short)bf16bits(a.z); v[3]=(short)bf16bits(a.w);
  v[4]=(short)bf16bits(b.x); v[5]=(short)bf16bits(b.y);
  v[6]=(short)bf16bits(b.z); v[7]=(short)bf16bits(b.w);
  return v;
}

// ---------- K1all: {k1 RevIN+EMA | k0 fold | k0b bias+Wsum} by blockIdx range ----------
__global__ __launch_bounds__(256) void k1_all(
    const float* __restrict__ x, const float* __restrict__ rev_w, const float* __restrict__ rev_b,
    const float* __restrict__ seas_w, const float* __restrict__ tr_w, const float* __restrict__ fus_w,
    const float* __restrict__ seas_b, const float* __restrict__ tr_b, const float* __restrict__ fus_b,
    const float* __restrict__ fc2_w,
    float* __restrict__ s_raw, __hip_bfloat16* __restrict__ t_bf, float* __restrict__ rowpar,
    float* __restrict__ pooled,
    __hip_bfloat16* __restrict__ Wsf, __hip_bfloat16* __restrict__ Wtf,
    float* __restrict__ biasc, float* __restrict__ colsumT, float* __restrict__ Wsum) {
  __shared__ float lf[8][32];
  __shared__ float psum[8][32], psq[8][32];
  __shared__ float fs[8][32];
  __shared__ float st[32*STW_];
  int tid = threadIdx.x;
  int bid = blockIdx.x;
  if (bid >= BC_/32) {
    int fb = bid - BC_/32;
    if (fb < 576) {
      int idx = fb*256 + tid;
      int j = idx / 1536, k = idx - j*1536;
      float acc = 0.f;
      if (k < 1024) {
        for (int i=0;i<96;++i) acc = fmaf(fus_w[j*192+i], seas_w[i*1024+k], acc);
        Wsf[(size_t)j*1024 + k] = __float2bfloat16(acc);
      } else {
        int l = k - 1024;
        for (int i=0;i<96;++i) acc = fmaf(fus_w[j*192+96+i], tr_w[i*512+l], acc);
        Wtf[(size_t)j*512 + l] = __float2bfloat16(acc);
      }
    } else {
      __shared__ float rowsum[96];
      if (tid >= 96 && tid < 112) {
        int j = tid - 96;
        float s = 0.f;
        #pragma unroll
        for (int k=0;k<32;++k) s += fc2_w[j*32+k];
        Wsum[j] = s;
      }
      if (tid < 96) {
        float s = 0.f;
        for (int l=0;l<512;++l) s += tr_w[tid*512+l];
        rowsum[tid] = s;
      }
      __syncthreads();
      if (tid < 96) {
        float acc = fus_b[tid], cs = 0.f;
        for (int i=0;i<96;++i) {
          acc = fmaf(fus_w[tid*192+i],    seas_b[i], acc);
          acc = fmaf(fus_w[tid*192+96+i], tr_b[i],   acc);
          cs  = fmaf(fus_w[tid*192+96+i], rowsum[i], cs);
        }
        biasc[tid] = acc; colsumT[tid] = cs;
      }
    }
    return;
  }
  int q = tid >> 5, r = tid & 31;
  int row0 = bid*32;
  int row = row0 + r;
  int b = row / C_, c = row - b*C_;
  const float* xp = x + (size_t)b*L_*C_ + c;
  int l0 = q*64;
  float sreg[64];
  float loc = 0.f, sum = 0.f, sq = 0.f;
  #pragma unroll
  for (int i=0;i<64;++i) {
    float v = xp[(size_t)(l0+i)*C_];
    sum += v; sq = fmaf(v,v,sq);
    loc = (q==0 && i==0) ? v : fmaf(ALPHA_, v, 0.8f*loc);
    sreg[i] = loc;
  }
  lf[q][r] = loc; psum[q][r] = sum; psq[q][r] = sq;
  __syncthreads();
  float cin = 0.f;
  for (int j=0;j<q;++j) cin = fmaf(D64_, cin, lf[j][r]);
  float S=0.f, Q=0.f;
  #pragma unroll
  for (int qq=0;qq<8;++qq){ S += psum[qq][r]; Q += psq[qq][r]; }
  float mean = S*(1.0f/512.0f);
  float var  = (Q - S*S*(1.0f/512.0f))*(1.0f/511.0f);
  var = fmaxf(var, 0.f);
  float stdv = sqrtf(var) + EPS_;
  float rwc = rev_w[c];
  float a = rwc / stdv;
  if (q==0) {
    float rbc = rev_b[c];
    float g = rbc - mean*a;
    float inva = stdv / rwc;
    ((float4*)rowpar)[row] = make_float4(a, g, mean, inva);
  }
  float prev = 0.f, f = 1.f, slast = 0.f;
  float sums8[8];
  #pragma unroll
  for (int j=0;j<8;++j) sums8[j] = 0.f;
  #pragma unroll
  for (int i=0;i<64;++i) {
    float lc = sreg[i];
    f *= 0.8f;
    float s = (q==0 && i==0) ? 0.f : fmaf(4.f, lc - prev, -f*cin);
    prev = lc;
    float sv = s * a;
    st[r*STW_ + q*64 + i] = sv;
    sums8[i>>3] += sv;
    slast = sv;
  }
  fs[q][r] = sums8[0];
  if (q==7) {
    #pragma unroll
    for (int k=0;k<8;++k) st[r*STW_ + 512 + k] = slast;
  }
  __syncthreads();
  for (int idx=tid; idx<32*130; idx+=256) {
    int rr = idx/130, g = idx - rr*130;
    float4 v = *(float4*)&st[rr*STW_ + g*4];
    *(float4*)&s_raw[(size_t)(row0+rr)*SROW_ + g*4] = v;
  }
  {
    float nf = (q < 7) ? fs[q+1][r] : 8.0f*slast;
    #pragma unroll
    for (int j=0;j<7;++j)
      pooled[(size_t)row*64 + q*8 + j] = (sums8[j] + sums8[j+1])*(1.0f/16.0f);
    pooled[(size_t)row*64 + q*8 + 7] = (sums8[7] + nf)*(1.0f/16.0f);
  }
  __syncthreads();
  unsigned* tb = (unsigned*)st;
  {
    float f2 = 1.f; unsigned lo = 0;
    #pragma unroll
    for (int i=0;i<64;++i) {
      f2 *= 0.8f;
      float tt = fmaf(f2, cin, sreg[i]) * a;
      unsigned hb = bf16bits(tt);
      if ((i&1)==0) lo = hb;
      else tb[r*UTW_ + q*32 + (i>>1)] = lo | (hb<<16);
    }
  }
  __syncthreads();
  for (int idx=tid; idx<32*64; idx+=256) {
    int rr = idx>>6, g = idx&63;
    uint4 v = *(uint4*)&tb[rr*UTW_ + g*4];
    *(uint4*)&t_bf[(size_t)(row0+rr)*512 + g*8] = v;
  }
}

// ---------- K4: gate MLP via MFMA (two chained bf16 GEMMs) ----------
__global__ __launch_bounds__(512) void k4_gate(
    const float* __restrict__ pooled,
    const float* __restrict__ m1_w, const float* __restrict__ m1_b,
    const float* __restrict__ m2_w, const float* __restrict__ m2_b,
    float* __restrict__ wl_g) {
  __shared__ __align__(16) __hip_bfloat16 buf[17408];
  int t = threadIdx.x;
  int row0 = blockIdx.x*64;
  __hip_bfloat16* A1 = buf;
  __hip_bfloat16* B1 = buf + 4608;
  __hip_bfloat16* H1 = buf;
  __hip_bfloat16* B2 = buf + 8704;
  for (int idx=t; idx<4096; idx+=512) {
    int r = idx>>6, k = idx&63;
    A1[r*72+k] = __float2bfloat16(pooled[(size_t)(row0+r)*64 + k]);
  }
  for (int idx=t; idx<8192; idx+=512) {
    int r = idx>>6, k = idx&63;
    B1[r*72+k] = __float2bfloat16(m1_w[idx]);
  }
  __syncthreads();
  int lane = t & 63, w = t >> 6;
  int fr = lane & 15, fg = lane >> 4;
  int mt = w & 3;
  int ng0 = (w>>2)*4;
  f32x4 acc1[4];
  #pragma unroll
  for (int nn=0;nn<4;++nn) acc1[nn] = (f32x4){0.f,0.f,0.f,0.f};
  #pragma unroll
  for (int ksub=0; ksub<2; ++ksub) {
    bf16x8 av = *(bf16x8*)&A1[(mt*16+fr)*72 + ksub*32 + fg*8];
    #pragma unroll
    for (int nn=0;nn<4;++nn) {
      bf16x8 bv = *(bf16x8*)&B1[((ng0+nn)*16+fr)*72 + ksub*32 + fg*8];
      acc1[nn] = __builtin_amdgcn_mfma_f32_16x16x32_bf16(av, bv, acc1[nn], 0,0,0);
    }
  }
  __syncthreads();
  #pragma unroll
  for (int nn=0;nn<4;++nn) {
    int col = (ng0+nn)*16 + fr;
    float bias = m1_b[col];
    #pragma unroll
    for (int reg=0;reg<4;++reg) {
      int row = mt*16 + fg*4 + reg;
      H1[row*136 + col] = __float2bfloat16(gelu_f(acc1[nn][reg] + bias));
    }
  }
  for (int idx=t; idx<8192; idx+=512) {
    int r = idx>>7, k = idx&127;
    B2[r*136+k] = __float2bfloat16(m2_w[idx]);
  }
  __syncthreads();
  int nt0 = (w>>2)*2;
  f32x4 acc2[2];
  #pragma unroll
  for (int nn=0;nn<2;++nn) acc2[nn] = (f32x4){0.f,0.f,0.f,0.f};
  #pragma unroll
  for (int ksub=0; ksub<4; ++ksub) {
    bf16x8 av = *(bf16x8*)&H1[(mt*16+fr)*136 + ksub*32 + fg*8];
    #pragma unroll
    for (int nn=0;nn<2;++nn) {
      bf16x8 bv = *(bf16x8*)&B2[((nt0+nn)*16+fr)*136 + ksub*32 + fg*8];
      acc2[nn] = __builtin_amdgcn_mfma_f32_16x16x32_bf16(av, bv, acc2[nn], 0,0,0);
    }
  }
  #pragma unroll
  for (int nn=0;nn<2;++nn) {
    int col = (nt0+nn)*16 + fr;
    float bias = m2_b[col];
    #pragma unroll
    for (int reg=0;reg<4;++reg) {
      int row = mt*16 + fg*4 + reg;
      wl_g[(size_t)(row0+row)*64 + col] = 1.0f/(1.0f + __expf(-(acc2[nn][reg] + bias)));
    }
  }
}

// ---------- K2 (fallback): BN1 statistics ----------
__global__ __launch_bounds__(256) void k2_bn1stats(
    const float* __restrict__ s_raw,
    const float* __restrict__ fc1_w, const float* __restrict__ fc1_b,
    float* __restrict__ partials) {
  __shared__ float sl[GR_*SROW_];
  __shared__ float red[2][GR_*64];
  int t = threadIdx.x;
  int row0 = blockIdx.x*GR_;
  for (int idx=t; idx<GR_*520; idx+=256) {
    int rr = idx/520, cc = idx - rr*520;
    sl[rr*SROW_+cc] = s_raw[(size_t)(row0+rr)*SROW_+cc];
  }
  __syncthreads();
  int lr = t >> 4, ng = t & 15;
  for (int q=0;q<4;++q) {
    int n = ng + 16*q;
    float sp[16];
    #pragma unroll
    for (int p=0;p<16;++p) sp[p] = sl[lr*SROW_ + n*8 + p];
    float s1=0.f, s2=0.f;
    #pragma unroll
    for (int hid=0; hid<32; ++hid) {
      float acc = fc1_b[hid];
      #pragma unroll
      for (int p=0;p<16;++p) acc = fmaf(sp[p], fc1_w[hid*16+p], acc);
      float gv = gelu_f(acc);
      s1 += gv; s2 = fmaf(gv,gv,s2);
    }
    red[0][lr*64+n] = s1;
    red[1][lr*64+n] = s2;
  }
  __syncthreads();
  if (t < 64) {
    float S1=0.f, S2=0.f;
    for (int lr2=0; lr2<GR_; ++lr2) { S1 += red[0][lr2*64+t]; S2 += red[1][lr2*64+t]; }
    partials[((size_t)blockIdx.x*64+t)*2+0] = S1;
    partials[((size_t)blockIdx.x*64+t)*2+1] = S2;
  }
}

// ---------- K2v6: fc1 via swapped MFMA; bn1 stats ONLY (no crp materialization) ----------
// n = mt*16+fr is w-independent; per-(mt,fr) partials land in red[.][mt][fr][w*4+fg],
// stride 33 to avoid the 16-way bank alias; t<64 reduces 32 slots for n=t.
__global__ __launch_bounds__(512) void k2v6_bn1stats(
    const float* __restrict__ s_raw,
    const float* __restrict__ fc1_w, const float* __restrict__ fc1_b,
    float* __restrict__ partials) {
  __shared__ float red[2][4][16][33];
  int t = threadIdx.x;
  int row0 = blockIdx.x*8;
  int lane = t & 63, w = t >> 6;
  int fr = lane & 15, fg = lane >> 4;
  bf16x8 z8 = (bf16x8){0,0,0,0,0,0,0,0};
  bf16x8 wv0 = (fg < 2) ? cvt8(&fc1_w[fr*16 + fg*8]) : z8;
  bf16x8 wv1 = (fg < 2) ? cvt8(&fc1_w[(16+fr)*16 + fg*8]) : z8;
  float4 b40 = ((const float4*)fc1_b)[fg];
  float4 b41 = ((const float4*)fc1_b)[4+fg];
  #pragma unroll
  for (int mt=0;mt<4;++mt) {
    int p = (w*4+mt)*16 + fr;
    int lr = p>>6, n = p&63;
    bf16x8 pv = (fg < 2) ? cvt8(&s_raw[(size_t)(row0+lr)*SROW_ + n*8 + fg*8]) : z8;
    f32x4 a0 = (f32x4){0.f,0.f,0.f,0.f};
    f32x4 a1 = (f32x4){0.f,0.f,0.f,0.f};
    a0 = __builtin_amdgcn_mfma_f32_16x16x32_bf16(wv0, pv, a0, 0,0,0);
    a1 = __builtin_amdgcn_mfma_f32_16x16x32_bf16(wv1, pv, a1, 0,0,0);
    float s1=0.f, s2=0.f;
    float bb0[4] = {b40.x,b40.y,b40.z,b40.w};
    float bb1[4] = {b41.x,b41.y,b41.z,b41.w};
    #pragma unroll
    for (int reg=0;reg<4;++reg) {
      float g0 = gelu_f(a0[reg] + bb0[reg]);
      float g1 = gelu_f(a1[reg] + bb1[reg]);
      s1 += g0 + g1;
      s2 = fmaf(g0,g0, fmaf(g1,g1, s2));
    }
    red[0][mt][fr][w*4+fg] = s1;
    red[1][mt][fr][w*4+fg] = s2;
  }
  __syncthreads();
  if (t < 64) {
    int mtn = t>>4, frn = t&15;
    float S1=0.f, S2=0.f;
    #pragma unroll
    for (int i=0;i<32;++i) { S1 += red[0][mtn][frn][i]; S2 += red[1][mtn][frn][i]; }
    partials[((size_t)blockIdx.x*64+t)*2+0] = S1;
    partials[((size_t)blockIdx.x*64+t)*2+1] = S2;
  }
}

// ---------- bn reduce ----------
__global__ __launch_bounds__(256) void k_bnreduce(
    const float* __restrict__ partials, int nblk,
    const float* __restrict__ bnw, const float* __restrict__ bnb,
    float* __restrict__ scale, float* __restrict__ shift) {
  __shared__ float red[2][256];
  int n = blockIdx.x, t = threadIdx.x;
  float s1=0.f, s2=0.f;
  for (int i=t; i<nblk; i+=256) {
    s1 += partials[((size_t)i*64+n)*2+0];
    s2 += partials[((size_t)i*64+n)*2+1];
  }
  red[0][t]=s1; red[1][t]=s2;
  __syncthreads();
  for (int off=128; off>0; off>>=1) {
    if (t<off) { red[0][t]+=red[0][t+off]; red[1][t]+=red[1][t+off]; }
    __syncthreads();
  }
  if (t==0) {
    const float count = (float)BC_ * 32.0f;
    float mu = red[0][0]/count;
    float var = red[1][0]/count - mu*mu;
    float sc = rsqrtf(var + EPS_) * bnw[n];
    scale[n] = sc;
    shift[n] = bnb[n] - mu*sc;
  }
}

// ---------- K3 (fallback): BN2 statistics ----------
__global__ __launch_bounds__(256) void k3_bn2stats(
    const float* __restrict__ s_raw,
    const float* __restrict__ fc1_w, const float* __restrict__ fc1_b,
    const float* __restrict__ scale1, const float* __restrict__ shift1,
    const float* __restrict__ conv_w, const float* __restrict__ conv_b,
    float* __restrict__ partials) {
  __shared__ float sl[GR_*SROW_];
  __shared__ float sc1[64], sh1[64], cw[192], cb[64];
  __shared__ float red[2][GR_*64];
  int t = threadIdx.x;
  int row0 = blockIdx.x*GR_;
  if (t < 64) { sc1[t]=scale1[t]; sh1[t]=shift1[t]; cb[t]=conv_b[t]; }
  if (t >= 64 && t < 256) cw[t-64] = conv_w[t-64];
  __syncthreads();
  for (int idx=t; idx<GR_*520; idx+=256) {
    int rr = idx/520, cc = idx - rr*520;
    sl[rr*SROW_+cc] = s_raw[(size_t)(row0+rr)*SROW_+cc];
  }
  __syncthreads();
  int lr = t >> 4, ng = t & 15;
  for (int q=0;q<4;++q) {
    int n = ng + 16*q;
    float sp[16];
    #pragma unroll
    for (int p=0;p<16;++p) sp[p] = sl[lr*SROW_ + n*8 + p];
    float scn = sc1[n], shn = sh1[n];
    float h[32];
    #pragma unroll
    for (int hid=0; hid<32; ++hid) {
      float acc = fc1_b[hid];
      #pragma unroll
      for (int p=0;p<16;++p) acc = fmaf(sp[p], fc1_w[hid*16+p], acc);
      h[hid] = fmaf(gelu_f(acc), scn, shn);
    }
    float w0=cw[n*3], wm=cw[n*3+1], wpp=cw[n*3+2], cbn=cb[n];
    float s1=0.f, s2=0.f, prev=0.f;
    #pragma unroll
    for (int k2=0;k2<32;++k2) {
      float cur = h[k2];
      float cv = cbn;
      cv = fmaf(prev, w0, cv);
      cv = fmaf(cur, wm, cv);
      if (k2<31) cv = fmaf(h[k2+1], wpp, cv);
      float gv = gelu_f(cv);
      s1 += gv; s2 = fmaf(gv,gv,s2);
      prev = cur;
    }
    red[0][lr*64+n]=s1; red[1][lr*64+n]=s2;
  }
  __syncthreads();
  if (t < 64) {
    float S1=0.f, S2=0.f;
    for (int lr2=0; lr2<GR_; ++lr2) { S1 += red[0][lr2*64+t]; S2 += red[1][lr2*64+t]; }
    partials[((size_t)blockIdx.x*64+t)*2+0] = S1;
    partials[((size_t)blockIdx.x*64+t)*2+1] = S2;
  }
}

// ---------- K3v4: recompute fc1 (MFMA) + conv from s_raw; bn2 stats + U (no crp) ----------
// Phase 1 = k2v5's MFMA+gelu -> Hb (bf16 g1, chunk-major). Phase 2 = conv + bn1-affine
// + gelu + stats + U fused per-k with u[16] accumulators (fc2_w loads are wave-uniform).
__global__ __launch_bounds__(512) void k3v4_bn2_u(
    const float* __restrict__ s_raw,
    const float* __restrict__ fc1_w, const float* __restrict__ fc1_b,
    const float* __restrict__ scale1, const float* __restrict__ shift1,
    const float* __restrict__ conv_w, const float* __restrict__ conv_b,
    const float* __restrict__ fc2_w,
    float* __restrict__ partials, __half* __restrict__ Ub) {
  __shared__ __align__(16) __hip_bfloat16 Hb[4*512*8];   // [hid>>3][patch][hid&7] 32 KB
  __shared__ float sc1[64], sh0l[64], shml[64], sh31l[64];
  __shared__ float cw[192];
  __shared__ float red[2][512];
  int t = threadIdx.x;
  int row0 = blockIdx.x*8;
  if (t < 64) {
    float w0=conv_w[t*3], wm=conv_w[t*3+1], wp=conv_w[t*3+2];
    float s1v=shift1[t], cbv=conv_b[t];
    sc1[t]  = scale1[t];
    sh0l[t] = fmaf(s1v, wm+wp, cbv);
    shml[t] = fmaf(s1v, w0+wm+wp, cbv);
    sh31l[t]= fmaf(s1v, w0+wm, cbv);
  }
  if (t >= 64 && t < 256) cw[t-64] = conv_w[t-64];
  int lane = t & 63, w = t >> 6;
  int fr = lane & 15, fg = lane >> 4;
  bf16x8 z8 = (bf16x8){0,0,0,0,0,0,0,0};
  bf16x8 wv0 = (fg < 2) ? cvt8(&fc1_w[fr*16 + fg*8]) : z8;
  bf16x8 wv1 = (fg < 2) ? cvt8(&fc1_w[(16+fr)*16 + fg*8]) : z8;
  f32x4 acc[4][2];
  #pragma unroll
  for (int mt=0;mt<4;++mt)
    #pragma unroll
    for (int nt=0;nt<2;++nt) acc[mt][nt] = (f32x4){0.f,0.f,0.f,0.f};
  #pragma unroll
  for (int mt=0;mt<4;++mt) {
    int p = (w*4+mt)*16 + fr;
    int lr = p>>6, n = p&63;
    bf16x8 pv = (fg < 2) ? cvt8(&s_raw[(size_t)(row0+lr)*SROW_ + n*8 + fg*8]) : z8;
    acc[mt][0] = __builtin_amdgcn_mfma_f32_16x16x32_bf16(wv0, pv, acc[mt][0], 0,0,0);
    acc[mt][1] = __builtin_amdgcn_mfma_f32_16x16x32_bf16(wv1, pv, acc[mt][1], 0,0,0);
  }
  #pragma unroll
  for (int mt=0;mt<4;++mt) {
    int p = (w*4+mt)*16 + fr;
    #pragma unroll
    for (int nt=0;nt<2;++nt) {
      float4 b4 = ((const float4*)fc1_b)[nt*4+fg];
      float g0 = gelu_f(acc[mt][nt][0] + b4.x);
      float g1 = gelu_f(acc[mt][nt][1] + b4.y);
      float g2 = gelu_f(acc[mt][nt][2] + b4.z);
      float g3 = gelu_f(acc[mt][nt][3] + b4.w);
      unsigned lo = (unsigned)bf16bits(g0) | (((unsigned)bf16bits(g1))<<16);
      unsigned hi = (unsigned)bf16bits(g2) | (((unsigned)bf16bits(g3))<<16);
      int hb = nt*16 + fg*4;
      *(uint2*)&Hb[(hb>>3)*4096 + p*8 + (hb&7)] = make_uint2(lo, hi);
    }
  }
  __syncthreads();
  {
    int n = t & 63;
    uint4 u0 = *(const uint4*)&Hb[0*4096 + t*8];
    uint4 u1 = *(const uint4*)&Hb[1*4096 + t*8];
    uint4 u2 = *(const uint4*)&Hb[2*4096 + t*8];
    uint4 u3 = *(const uint4*)&Hb[3*4096 + t*8];
    unsigned uw[16] = {u0.x,u0.y,u0.z,u0.w, u1.x,u1.y,u1.z,u1.w,
                       u2.x,u2.y,u2.z,u2.w, u3.x,u3.y,u3.z,u3.w};
    float g[32];
    #pragma unroll
    for (int j=0;j<16;++j) {
      g[2*j]   = __uint_as_float(uw[j]<<16);
      g[2*j+1] = __uint_as_float(uw[j] & 0xffff0000u);
    }
    float w0=cw[n*3], wm=cw[n*3+1], wp=cw[n*3+2];
    float sc1n = sc1[n];
    float shm = shml[n], sh0 = sh0l[n], sh31 = sh31l[n];
    float u[16];
    #pragma unroll
    for (int jj=0;jj<16;++jj) u[jj] = 0.f;
    float s1=0.f, s2=0.f, prevv=0.f;
    #pragma unroll
    for (int k=0;k<32;++k) {
      float cr = fmaf(prevv, w0, fmaf(g[k], wm, (k<31) ? g[k+1]*wp : 0.f));
      prevv = g[k];
      float sh = (k==0) ? sh0 : ((k==31) ? sh31 : shm);
      float gv = gelu_f(fmaf(cr, sc1n, sh));
      s1 += gv; s2 = fmaf(gv,gv,s2);
      #pragma unroll
      for (int jj=0;jj<16;++jj) u[jj] = fmaf(fc2_w[jj*32+k], gv, u[jj]);
    }
    unsigned wds[8];
    #pragma unroll
    for (int jj=0;jj<8;++jj)
      wds[jj] = (unsigned)f16bits(u[2*jj]) | (((unsigned)f16bits(u[2*jj+1]))<<16);
    uint4* dst = (uint4*)&Ub[((size_t)row0*64 + t)*16];
    dst[0] = make_uint4(wds[0],wds[1],wds[2],wds[3]);
    dst[1] = make_uint4(wds[4],wds[5],wds[6],wds[7]);
    red[0][t]=s1; red[1][t]=s2;
  }
  __syncthreads();
  if (t < 64) {
    float S1=0.f, S2=0.f;
    #pragma unroll
    for (int lr2=0; lr2<8; ++lr2) { S1 += red[0][lr2*64+t]; S2 += red[1][lr2*64+t]; }
    partials[((size_t)blockIdx.x*64+t)*2+0] = S1;
    partials[((size_t)blockIdx.x*64+t)*2+1] = S2;
  }
}

// ---------- K5a (fallback): full per-row pipeline ----------
__global__ __launch_bounds__(256) void k5a_pipeline(
    const float* __restrict__ s_raw, const float* __restrict__ wl_g,
    const float* __restrict__ fc1_w, const float* __restrict__ fc1_b,
    const float* __restrict__ scale1, const float* __restrict__ shift1,
    const float* __restrict__ conv_w, const float* __restrict__ conv_b,
    const float* __restrict__ scale2, const float* __restrict__ shift2,
    const float* __restrict__ fc2_w, const float* __restrict__ fc2_b,
    const float* __restrict__ gl_scale,
    const float* __restrict__ ln_w, const float* __restrict__ ln_b,
    __hip_bfloat16* __restrict__ ybf) {
  __shared__ float sl[RB_*SROW_];
  __shared__ float cw[192], cb[64];
  __shared__ float sc1[64], sh1[64], sc2[64], sh2[64];
  int t = threadIdx.x;
  int row0 = blockIdx.x*RB_;
  if (t<64) { sc1[t]=scale1[t]; sh1[t]=shift1[t]; sc2[t]=scale2[t]; sh2[t]=shift2[t]; cb[t]=conv_b[t]; }
  if (t>=64 && t<256) cw[t-64]=conv_w[t-64];
  __syncthreads();
  for (int idx=t; idx<RB_*520; idx+=256) {
    int rr = idx/520, cc = idx - rr*520;
    sl[rr*SROW_+cc] = s_raw[(size_t)(row0+rr)*SROW_+cc];
  }
  __syncthreads();
  float glv = gl_scale[0];
  for (int idx=t; idx<RB_*64; idx+=256) {
    int rr = idx>>6, n = idx&63;
    float wlv = wl_g[(size_t)row0*64 + idx];
    float h[32];
    {
      float sp[16];
      #pragma unroll
      for (int p=0;p<16;++p) sp[p] = sl[rr*SROW_ + n*8 + p];
      float scn=sc1[n], shn=sh1[n];
      #pragma unroll
      for (int hid=0;hid<32;++hid) {
        float acc=fc1_b[hid];
        #pragma unroll
        for (int p=0;p<16;++p) acc=fmaf(sp[p], fc1_w[hid*16+p], acc);
        h[hid]=fmaf(gelu_f(acc), scn, shn);
      }
    }
    {
      float w0=cw[n*3], wm=cw[n*3+1], wpp=cw[n*3+2], cbn=cb[n];
      float sc2n=sc2[n], sh2n=sh2[n];
      float prev=0.f;
      #pragma unroll
      for (int k2=0;k2<32;++k2) {
        float cur = h[k2];
        float cv = cbn;
        cv = fmaf(prev, w0, cv);
        cv = fmaf(cur, wm, cv);
        if (k2<31) cv = fmaf(h[k2+1], wpp, cv);
        h[k2] = fmaf(gelu_f(cv), sc2n, sh2n);
        prev = cur;
      }
    }
    float yv[16];
    #pragma unroll
    for (int p=0;p<16;++p) {
      float acc=fc2_b[p];
      #pragma unroll
      for (int hid=0;hid<32;++hid) acc=fmaf(h[hid], fc2_w[p*32+hid], acc);
      yv[p]=acc;
    }
    float smul = 3.0f + glv*wlv;
    float mu=0.f;
    #pragma unroll
    for (int p=0;p<16;++p) {
      yv[p]=fmaf(sl[rr*SROW_ + n*8 + p], smul, yv[p]);
      mu+=yv[p];
    }
    mu *= (1.0f/16.0f);
    float var=0.f;
    #pragma unroll
    for (int p=0;p<16;++p){ float d=yv[p]-mu; var=fmaf(d,d,var); }
    var *= (1.0f/16.0f);
    float rs = rsqrtf(var + EPS_);
    unsigned int wds[8];
    #pragma unroll
    for (int j=0;j<8;++j) {
      unsigned int lo = bf16bits(fmaf((yv[2*j]-mu)*rs,   ln_w[2*j],   ln_b[2*j]));
      unsigned int hi = bf16bits(fmaf((yv[2*j+1]-mu)*rs, ln_w[2*j+1], ln_b[2*j+1]));
      wds[j] = lo | (hi<<16);
    }
    size_t ybase = (size_t)(row0+rr)*1024 + n*16;
    uint4* dst = (uint4*)&ybf[ybase];
    dst[0] = make_uint4(wds[0],wds[1],wds[2],wds[3]);
    dst[1] = make_uint4(wds[4],wds[5],wds[6],wds[7]);
  }
}

// ---------- K5a_v4: read U (fp16, aliased in ybf region), bn2 affine via linearity,
// residual + LN, overwrite same 32B with y (per-thread in-place) ----------
__global__ __launch_bounds__(512) void k5a_v4(
    const float* __restrict__ s_raw, const float* __restrict__ wl_g,
    const float* __restrict__ scale2, const float* __restrict__ shift2,
    const float* __restrict__ Wsum, const float* __restrict__ fc2_b,
    const float* __restrict__ gl_scale,
    const float* __restrict__ ln_w, const float* __restrict__ ln_b,
    __hip_bfloat16* __restrict__ ybf) {
  __shared__ float sc2l[64], sh2l[64];
  int t = threadIdx.x;
  int row0 = blockIdx.x*RB_;
  if (t < 64) { sc2l[t]=scale2[t]; sh2l[t]=shift2[t]; }
  __syncthreads();
  int rr = t>>6, n = t&63;
  int row = row0 + rr;
  float glv = gl_scale[0];
  float wlv = wl_g[(size_t)row*64 + n];
  size_t pbase = ((size_t)row*64 + n)*16;
  uint4* uptr = (uint4*)&ybf[pbase];
  uint4 a = uptr[0], b = uptr[1];
  unsigned hw[8] = {a.x,a.y,a.z,a.w, b.x,b.y,b.z,b.w};
  float sc2n = sc2l[n], sh2n = sh2l[n];
  float yv[16];
  #pragma unroll
  for (int j=0;j<8;++j) {
    float U0 = f16val((unsigned short)(hw[j] & 0xffffu));
    float U1 = f16val((unsigned short)(hw[j] >> 16));
    yv[2*j]   = fmaf(sc2n, U0, fmaf(sh2n, Wsum[2*j],   fc2_b[2*j]));
    yv[2*j+1] = fmaf(sc2n, U1, fmaf(sh2n, Wsum[2*j+1], fc2_b[2*j+1]));
  }
  const float* sp_g = &s_raw[(size_t)row*SROW_ + n*8];
  float4 s0 = *(const float4*)(sp_g);
  float4 s1v = *(const float4*)(sp_g+4);
  float4 s2v = *(const float4*)(sp_g+8);
  float4 s3 = *(const float4*)(sp_g+12);
  float sp[16] = {s0.x,s0.y,s0.z,s0.w, s1v.x,s1v.y,s1v.z,s1v.w,
                  s2v.x,s2v.y,s2v.z,s2v.w, s3.x,s3.y,s3.z,s3.w};
  float smul = 3.0f + glv*wlv;
  float mu=0.f;
  #pragma unroll
  for (int p=0;p<16;++p) {
    yv[p] = fmaf(sp[p], smul, yv[p]);
    mu += yv[p];
  }
  mu *= (1.0f/16.0f);
  float var=0.f;
  #pragma unroll
  for (int p=0;p<16;++p){ float d=yv[p]-mu; var=fmaf(d,d,var); }
  var *= (1.0f/16.0f);
  float rs = rsqrtf(var + EPS_);
  unsigned int wds[8];
  #pragma unroll
  for (int j=0;j<8;++j) {
    unsigned int lo = bf16bits(fmaf((yv[2*j]-mu)*rs,   ln_w[2*j],   ln_b[2*j]));
    unsigned int hi = bf16bits(fmaf((yv[2*j+1]-mu)*rs, ln_w[2*j+1], ln_b[2*j+1]));
    wds[j] = lo | (hi<<16);
  }
  uptr[0] = make_uint4(wds[0],wds[1],wds[2],wds[3]);
  uptr[1] = make_uint4(wds[4],wds[5],wds[6],wds[7]);
}

// ---------- K5b: M=16 rows/block, 6 waves x 16 cols, LDS-staged (coalesced), 1-step reg prefetch ----------
__global__ __launch_bounds__(384) void k5b_gemm(
    const __hip_bfloat16* __restrict__ ybf, const __hip_bfloat16* __restrict__ tbf,
    const __hip_bfloat16* __restrict__ Wsf, const __hip_bfloat16* __restrict__ Wtf,
    const float* __restrict__ rowpar, const float* __restrict__ rev_b,
    const float* __restrict__ biasc, const float* __restrict__ colsumT,
    float* __restrict__ out) {
  __shared__ __align__(16) __hip_bfloat16 As[2*16*72];
  __shared__ __align__(16) __hip_bfloat16 Bs[2*96*72];
  __shared__ float rp[64];
  __shared__ float rbl[16];
  __shared__ int   obase[16];
  __shared__ float bcl[96], csl[96];
  int tid = threadIdx.x;
  int row0 = blockIdx.x*16;
  if (tid < 64) rp[tid] = rowpar[(size_t)row0*4 + tid];
  if (tid >= 64 && tid < 80) {
    int lr = tid-64;
    int row = row0 + lr; int b = row/C_; int c = row - b*C_;
    rbl[lr] = rev_b[c]; obase[lr] = b*PRED_*C_ + c;
  }
  if (tid >= 96 && tid < 192) { bcl[tid-96]=biasc[tid-96]; csl[tid-96]=colsumT[tid-96]; }
  int lane = tid & 63, w = tid >> 6;
  int fr = lane & 15, fg = lane >> 4;
  bool a0 = tid < 128;
  int r0 = a0 ? (tid>>3) : ((tid-128)>>3);
  int c0 = a0 ? (tid&7)  : ((tid-128)&7);
  int r1 = (tid+256)>>3, c1 = (tid+256)&7;
  bool h2 = tid < 128;
  int r2 = (tid+640)>>3, c2 = (tid+640)&7;
  f32x4 acc = (f32x4){0.f,0.f,0.f,0.f};

  uint4 v0, v1, v2;
  auto LOAD = [&](int ks){
    const __hip_bfloat16* Ag; const __hip_bfloat16* Bg; int K; int kofs;
    if (ks < 8) { Ag = tbf + (size_t)row0*512;  Bg = Wtf; K = 512;  kofs = ks*64; }
    else        { Ag = ybf + (size_t)row0*1024; Bg = Wsf; K = 1024; kofs = (ks-8)*64; }
    v0 = a0 ? *(const uint4*)(Ag + (size_t)r0*K + kofs + c0*8)
            : *(const uint4*)(Bg + (size_t)r0*K + kofs + c0*8);
    v1 = *(const uint4*)(Bg + (size_t)r1*K + kofs + c1*8);
    if (h2) v2 = *(const uint4*)(Bg + (size_t)r2*K + kofs + c2*8);
  };

  LOAD(0);
  int cur = 0;
  for (int ks=0; ks<24; ++ks) {
    __hip_bfloat16* Ab = &As[cur*16*72];
    __hip_bfloat16* Bb = &Bs[cur*96*72];
    if (a0) *(uint4*)&Ab[r0*72 + c0*8] = v0;
    else    *(uint4*)&Bb[r0*72 + c0*8] = v0;
    *(uint4*)&Bb[r1*72 + c1*8] = v1;
    if (h2) *(uint4*)&Bb[r2*72 + c2*8] = v2;
    __syncthreads();
    if (ks < 23) LOAD(ks+1);
    #pragma unroll
    for (int ksub=0; ksub<2; ++ksub) {
      bf16x8 av = *(bf16x8*)&Ab[fr*72 + ksub*32 + fg*8];
      bf16x8 bv = *(bf16x8*)&Bb[(w*16+fr)*72 + ksub*32 + fg*8];
      acc = __builtin_amdgcn_mfma_f32_16x16x32_bf16(av, bv, acc, 0,0,0);
    }
    cur ^= 1;
  }
  {
    int col = w*16 + fr;
    float cs = csl[col], bc = bcl[col];
    #pragma unroll
    for (int reg=0;reg<4;++reg) {
      int rloc = fg*4 + reg;
      float g = rp[rloc*4+1], meanv = rp[rloc*4+2], inva = rp[rloc*4+3];
      float val = acc[reg] + g*cs + bc;
      val = (val - rbl[rloc])*inva + meanv;
      out[(size_t)obase[rloc] + (size_t)col*C_] = val;
    }
  }
}

extern "C" void kernel_launch(void* const* d_in, const int* in_sizes, int n_in,
                              void* d_out, int out_size, void* d_ws, size_t ws_size,
                              hipStream_t stream) {
  const float* x      = (const float*)d_in[0];
  const float* rev_w  = (const float*)d_in[1];
  const float* rev_b  = (const float*)d_in[2];
  const float* fc1_w  = (const float*)d_in[3];
  const float* fc1_b  = (const float*)d_in[4];
  const float* bn1_w  = (const float*)d_in[5];
  const float* bn1_b  = (const float*)d_in[6];
  const float* conv_w = (const float*)d_in[7];
  const float* conv_b = (const float*)d_in[8];
  const float* bn2_w  = (const float*)d_in[9];
  const float* bn2_b  = (const float*)d_in[10];
  const float* fc2_w  = (const float*)d_in[11];
  const float* fc2_b  = (const float*)d_in[12];
  const float* m1_w   = (const float*)d_in[13];
  const float* m1_b   = (const float*)d_in[14];
  const float* m2_w   = (const float*)d_in[15];
  const float* m2_b   = (const float*)d_in[16];
  const float* gl     = (const float*)d_in[17];
  const float* ln_w   = (const float*)d_in[18];
  const float* ln_b   = (const float*)d_in[19];
  const float* seas_w = (const float*)d_in[20];
  const float* seas_b = (const float*)d_in[21];
  const float* tr_w   = (const float*)d_in[22];
  const float* tr_b   = (const float*)d_in[23];
  const float* fus_w  = (const float*)d_in[24];
  const float* fus_b  = (const float*)d_in[25];
  float* out = (float*)d_out;
  float* ws = (float*)d_ws;

  __hip_bfloat16* Wsf  = (__hip_bfloat16*)(ws);
  __hip_bfloat16* Wtf  = (__hip_bfloat16*)(ws + 49152);
  float* biasc   = ws + 73728;
  float* colsumT = ws + 73856;
  float* scale1  = ws + 73984;
  float* shift1  = ws + 74048;
  float* scale2  = ws + 74112;
  float* shift2  = ws + 74176;
  float* partials= ws + 74240;     // fallback partials; big path: first 16 floats = Wsum
  float* Wsum    = ws + 74240;
  float* rowpar  = ws + 238592;
  float* s_raw   = ws + 320768;
  __hip_bfloat16* t_bf = (__hip_bfloat16*)(ws + 11168000);
  __hip_bfloat16* ybf  = (__hip_bfloat16*)(ws + 16427264);
  float* pooled  = ws + 26945792;
  float* wl_g    = ws + 28260608;
  float* ppool   = ws + 26945792;   // big-path partials alias pooled (dead after k4)
  __half* Uh     = (__half*)ybf;    // U aliases ybf region (same per-patch 32B slots)
  const size_t NEED = (29575424ull + 21037056ull) * 4ull;   // ~202.5 MB (unchanged)
  bool big = (ws_size >= NEED);

  hipLaunchKernelGGL(k1_all, dim3(BC_/32 + 577), dim3(256), 0, stream,
    x, rev_w, rev_b, seas_w, tr_w, fus_w, seas_b, tr_b, fus_b, fc2_w,
    s_raw, t_bf, rowpar, pooled, Wsf, Wtf, biasc, colsumT, Wsum);
  hipLaunchKernelGGL(k4_gate, dim3(BC_/64), dim3(512), 0, stream, pooled, m1_w, m1_b, m2_w, m2_b, wl_g);
  if (big) {
    hipLaunchKernelGGL(k2v6_bn1stats, dim3(NBLKH_), dim3(512), 0, stream, s_raw, fc1_w, fc1_b, ppool);
    hipLaunchKernelGGL(k_bnreduce, dim3(64), dim3(256), 0, stream, ppool, NBLKH_, bn1_w, bn1_b, scale1, shift1);
    hipLaunchKernelGGL(k3v4_bn2_u, dim3(NBLKH_), dim3(512), 0, stream,
      s_raw, fc1_w, fc1_b, scale1, shift1, conv_w, conv_b, fc2_w, ppool, Uh);
    hipLaunchKernelGGL(k_bnreduce, dim3(64), dim3(256), 0, stream, ppool, NBLKH_, bn2_w, bn2_b, scale2, shift2);
    hipLaunchKernelGGL(k5a_v4, dim3(NBLKH_), dim3(512), 0, stream,
      s_raw, wl_g, scale2, shift2, Wsum, fc2_b, gl, ln_w, ln_b, ybf);
  } else {
    hipLaunchKernelGGL(k2_bn1stats, dim3(NBLK2_), dim3(256), 0, stream, s_raw, fc1_w, fc1_b, partials);
    hipLaunchKernelGGL(k_bnreduce, dim3(64), dim3(256), 0, stream, partials, NBLK2_, bn1_w, bn1_b, scale1, shift1);
    hipLaunchKernelGGL(k3_bn2stats, dim3(NBLK2_), dim3(256), 0, stream, s_raw, fc1_w, fc1_b, scale1, shift1, conv_w, conv_b, partials);
    hipLaunchKernelGGL(k_bnreduce, dim3(64), dim3(256), 0, stream, partials, NBLK2_, bn2_w, bn2_b, scale2, shift2);
    hipLaunchKernelGGL(k5a_pipeline, dim3(BC_/RB_), dim3(256), 0, stream,
      s_raw, wl_g, fc1_w, fc1_b, scale1, shift1, conv_w, conv_b,
      scale2, shift2, fc2_w, fc2_b, gl, ln_w, ln_b, ybf);
  }
  hipLaunchKernelGGL(k5b_gemm, dim3(BC_/16), dim3(384), 0, stream,
    ybf, t_bf, Wsf, Wtf, rowpar, rev_b, biasc, colsumT, out);
}

// Round 28
// 205.889 us; speedup vs baseline: 1.0983x; 1.0983x over previous
//
#include <hip/hip_runtime.h>
#include <hip/hip_bf16.h>
#include <hip/hip_fp16.h>
#include <math.h>

#define B_    64
#define L_    512
#define C_    321
#define PRED_ 96
#define N_    64
#define HID_  32
#define BC_   (B_*C_)   // 20544
#define SROW_ 528
#define EPS_  1e-5f
#define ALPHA_ 0.2f
#define GR_   16
#define RB_   8
#define NBLK2_ (BC_/GR_) // 1284
#define NBLKH_ (BC_/8)   // 2568
#define D64_  6.2771017353866808e-7f   // 0.8^64
#define STW_  548
#define UTW_  260

typedef __attribute__((ext_vector_type(8))) short bf16x8;
typedef __attribute__((ext_vector_type(4))) float f32x4;

__device__ __forceinline__ float gelu_f(float x){
  float ax = fabsf(x);
  float z  = ax * 0.70710678118654752440f;
  float t  = __builtin_amdgcn_rcpf(fmaf(0.3275911f, z, 1.0f));
  float poly = fmaf(fmaf(fmaf(fmaf(1.061405429f, t, -1.453152027f),
                   t, 1.421413741f), t, -0.284496736f), t, 0.254829592f) * t;
  float e  = __expf(-z*z);
  float erfp = fmaf(-poly, e, 1.0f);
  return fmaf(0.5f*ax, erfp, 0.5f*x);
}
__device__ __forceinline__ unsigned short bf16bits(float x){
  __hip_bfloat16 h = __float2bfloat16(x);
  return *(unsigned short*)&h;
}
__device__ __forceinline__ unsigned short f16bits(float x){
  __half h = __float2half(x);
  return *(unsigned short*)&h;
}
__device__ __forceinline__ float f16val(unsigned short u){
  __half h = *(__half*)&u;
  return __half2float(h);
}
__device__ __forceinline__ bf16x8 cvt8(const float* p){
  float4 a = *(const float4*)p;
  float4 b = *(const float4*)(p+4);
  bf16x8 v;
  v[0]=(short)bf16bits(a.x); v[1]=(short)bf16bits(a.y);
  v[2]=(short)bf16bits(a.z); v[3]=(short)bf16bits(a.w);
  v[4]=(short)bf16bits(b.x); v[5]=(short)bf16bits(b.y);
  v[6]=(short)bf16bits(b.z); v[7]=(short)bf16bits(b.w);
  return v;
}

// ---------- K1all: {k1 RevIN+EMA | k0 fold | k0b bias+Wsum} by blockIdx range ----------
__global__ __launch_bounds__(256) void k1_all(
    const float* __restrict__ x, const float* __restrict__ rev_w, const float* __restrict__ rev_b,
    const float* __restrict__ seas_w, const float* __restrict__ tr_w, const float* __restrict__ fus_w,
    const float* __restrict__ seas_b, const float* __restrict__ tr_b, const float* __restrict__ fus_b,
    const float* __restrict__ fc2_w,
    float* __restrict__ s_raw, __hip_bfloat16* __restrict__ t_bf, float* __restrict__ rowpar,
    float* __restrict__ pooled,
    __hip_bfloat16* __restrict__ Wsf, __hip_bfloat16* __restrict__ Wtf,
    float* __restrict__ biasc, float* __restrict__ colsumT, float* __restrict__ Wsum) {
  __shared__ float lf[8][32];
  __shared__ float psum[8][32], psq[8][32];
  __shared__ float fs[8][32];
  __shared__ float st[32*STW_];
  int tid = threadIdx.x;
  int bid = blockIdx.x;
  if (bid >= BC_/32) {
    int fb = bid - BC_/32;
    if (fb < 576) {
      int idx = fb*256 + tid;
      int j = idx / 1536, k = idx - j*1536;
      float acc = 0.f;
      if (k < 1024) {
        for (int i=0;i<96;++i) acc = fmaf(fus_w[j*192+i], seas_w[i*1024+k], acc);
        Wsf[(size_t)j*1024 + k] = __float2bfloat16(acc);
      } else {
        int l = k - 1024;
        for (int i=0;i<96;++i) acc = fmaf(fus_w[j*192+96+i], tr_w[i*512+l], acc);
        Wtf[(size_t)j*512 + l] = __float2bfloat16(acc);
      }
    } else {
      __shared__ float rowsum[96];
      if (tid >= 96 && tid < 112) {
        int j = tid - 96;
        float s = 0.f;
        #pragma unroll
        for (int k=0;k<32;++k) s += fc2_w[j*32+k];
        Wsum[j] = s;
      }
      if (tid < 96) {
        float s = 0.f;
        for (int l=0;l<512;++l) s += tr_w[tid*512+l];
        rowsum[tid] = s;
      }
      __syncthreads();
      if (tid < 96) {
        float acc = fus_b[tid], cs = 0.f;
        for (int i=0;i<96;++i) {
          acc = fmaf(fus_w[tid*192+i],    seas_b[i], acc);
          acc = fmaf(fus_w[tid*192+96+i], tr_b[i],   acc);
          cs  = fmaf(fus_w[tid*192+96+i], rowsum[i], cs);
        }
        biasc[tid] = acc; colsumT[tid] = cs;
      }
    }
    return;
  }
  int q = tid >> 5, r = tid & 31;
  int row0 = bid*32;
  int row = row0 + r;
  int b = row / C_, c = row - b*C_;
  const float* xp = x + (size_t)b*L_*C_ + c;
  int l0 = q*64;
  float sreg[64];
  float loc = 0.f, sum = 0.f, sq = 0.f;
  #pragma unroll
  for (int i=0;i<64;++i) {
    float v = xp[(size_t)(l0+i)*C_];
    sum += v; sq = fmaf(v,v,sq);
    loc = (q==0 && i==0) ? v : fmaf(ALPHA_, v, 0.8f*loc);
    sreg[i] = loc;
  }
  lf[q][r] = loc; psum[q][r] = sum; psq[q][r] = sq;
  __syncthreads();
  float cin = 0.f;
  for (int j=0;j<q;++j) cin = fmaf(D64_, cin, lf[j][r]);
  float S=0.f, Q=0.f;
  #pragma unroll
  for (int qq=0;qq<8;++qq){ S += psum[qq][r]; Q += psq[qq][r]; }
  float mean = S*(1.0f/512.0f);
  float var  = (Q - S*S*(1.0f/512.0f))*(1.0f/511.0f);
  var = fmaxf(var, 0.f);
  float stdv = sqrtf(var) + EPS_;
  float rwc = rev_w[c];
  float a = rwc / stdv;
  if (q==0) {
    float rbc = rev_b[c];
    float g = rbc - mean*a;
    float inva = stdv / rwc;
    ((float4*)rowpar)[row] = make_float4(a, g, mean, inva);
  }
  float prev = 0.f, f = 1.f, slast = 0.f;
  float sums8[8];
  #pragma unroll
  for (int j=0;j<8;++j) sums8[j] = 0.f;
  #pragma unroll
  for (int i=0;i<64;++i) {
    float lc = sreg[i];
    f *= 0.8f;
    float s = (q==0 && i==0) ? 0.f : fmaf(4.f, lc - prev, -f*cin);
    prev = lc;
    float sv = s * a;
    st[r*STW_ + q*64 + i] = sv;
    sums8[i>>3] += sv;
    slast = sv;
  }
  fs[q][r] = sums8[0];
  if (q==7) {
    #pragma unroll
    for (int k=0;k<8;++k) st[r*STW_ + 512 + k] = slast;
  }
  __syncthreads();
  for (int idx=tid; idx<32*130; idx+=256) {
    int rr = idx/130, g = idx - rr*130;
    float4 v = *(float4*)&st[rr*STW_ + g*4];
    *(float4*)&s_raw[(size_t)(row0+rr)*SROW_ + g*4] = v;
  }
  {
    float nf = (q < 7) ? fs[q+1][r] : 8.0f*slast;
    #pragma unroll
    for (int j=0;j<7;++j)
      pooled[(size_t)row*64 + q*8 + j] = (sums8[j] + sums8[j+1])*(1.0f/16.0f);
    pooled[(size_t)row*64 + q*8 + 7] = (sums8[7] + nf)*(1.0f/16.0f);
  }
  __syncthreads();
  unsigned* tb = (unsigned*)st;
  {
    float f2 = 1.f; unsigned lo = 0;
    #pragma unroll
    for (int i=0;i<64;++i) {
      f2 *= 0.8f;
      float tt = fmaf(f2, cin, sreg[i]) * a;
      unsigned hb = bf16bits(tt);
      if ((i&1)==0) lo = hb;
      else tb[r*UTW_ + q*32 + (i>>1)] = lo | (hb<<16);
    }
  }
  __syncthreads();
  for (int idx=tid; idx<32*64; idx+=256) {
    int rr = idx>>6, g = idx&63;
    uint4 v = *(uint4*)&tb[rr*UTW_ + g*4];
    *(uint4*)&t_bf[(size_t)(row0+rr)*512 + g*8] = v;
  }
}

// ---------- K4: gate MLP via MFMA (two chained bf16 GEMMs) ----------
__global__ __launch_bounds__(512) void k4_gate(
    const float* __restrict__ pooled,
    const float* __restrict__ m1_w, const float* __restrict__ m1_b,
    const float* __restrict__ m2_w, const float* __restrict__ m2_b,
    float* __restrict__ wl_g) {
  __shared__ __align__(16) __hip_bfloat16 buf[17408];
  int t = threadIdx.x;
  int row0 = blockIdx.x*64;
  __hip_bfloat16* A1 = buf;
  __hip_bfloat16* B1 = buf + 4608;
  __hip_bfloat16* H1 = buf;
  __hip_bfloat16* B2 = buf + 8704;
  for (int idx=t; idx<4096; idx+=512) {
    int r = idx>>6, k = idx&63;
    A1[r*72+k] = __float2bfloat16(pooled[(size_t)(row0+r)*64 + k]);
  }
  for (int idx=t; idx<8192; idx+=512) {
    int r = idx>>6, k = idx&63;
    B1[r*72+k] = __float2bfloat16(m1_w[idx]);
  }
  __syncthreads();
  int lane = t & 63, w = t >> 6;
  int fr = lane & 15, fg = lane >> 4;
  int mt = w & 3;
  int ng0 = (w>>2)*4;
  f32x4 acc1[4];
  #pragma unroll
  for (int nn=0;nn<4;++nn) acc1[nn] = (f32x4){0.f,0.f,0.f,0.f};
  #pragma unroll
  for (int ksub=0; ksub<2; ++ksub) {
    bf16x8 av = *(bf16x8*)&A1[(mt*16+fr)*72 + ksub*32 + fg*8];
    #pragma unroll
    for (int nn=0;nn<4;++nn) {
      bf16x8 bv = *(bf16x8*)&B1[((ng0+nn)*16+fr)*72 + ksub*32 + fg*8];
      acc1[nn] = __builtin_amdgcn_mfma_f32_16x16x32_bf16(av, bv, acc1[nn], 0,0,0);
    }
  }
  __syncthreads();
  #pragma unroll
  for (int nn=0;nn<4;++nn) {
    int col = (ng0+nn)*16 + fr;
    float bias = m1_b[col];
    #pragma unroll
    for (int reg=0;reg<4;++reg) {
      int row = mt*16 + fg*4 + reg;
      H1[row*136 + col] = __float2bfloat16(gelu_f(acc1[nn][reg] + bias));
    }
  }
  for (int idx=t; idx<8192; idx+=512) {
    int r = idx>>7, k = idx&127;
    B2[r*136+k] = __float2bfloat16(m2_w[idx]);
  }
  __syncthreads();
  int nt0 = (w>>2)*2;
  f32x4 acc2[2];
  #pragma unroll
  for (int nn=0;nn<2;++nn) acc2[nn] = (f32x4){0.f,0.f,0.f,0.f};
  #pragma unroll
  for (int ksub=0; ksub<4; ++ksub) {
    bf16x8 av = *(bf16x8*)&H1[(mt*16+fr)*136 + ksub*32 + fg*8];
    #pragma unroll
    for (int nn=0;nn<2;++nn) {
      bf16x8 bv = *(bf16x8*)&B2[((nt0+nn)*16+fr)*136 + ksub*32 + fg*8];
      acc2[nn] = __builtin_amdgcn_mfma_f32_16x16x32_bf16(av, bv, acc2[nn], 0,0,0);
    }
  }
  #pragma unroll
  for (int nn=0;nn<2;++nn) {
    int col = (nt0+nn)*16 + fr;
    float bias = m2_b[col];
    #pragma unroll
    for (int reg=0;reg<4;++reg) {
      int row = mt*16 + fg*4 + reg;
      wl_g[(size_t)(row0+row)*64 + col] = 1.0f/(1.0f + __expf(-(acc2[nn][reg] + bias)));
    }
  }
}

// ---------- K2 (fallback): BN1 statistics ----------
__global__ __launch_bounds__(256) void k2_bn1stats(
    const float* __restrict__ s_raw,
    const float* __restrict__ fc1_w, const float* __restrict__ fc1_b,
    float* __restrict__ partials) {
  __shared__ float sl[GR_*SROW_];
  __shared__ float red[2][GR_*64];
  int t = threadIdx.x;
  int row0 = blockIdx.x*GR_;
  for (int idx=t; idx<GR_*520; idx+=256) {
    int rr = idx/520, cc = idx - rr*520;
    sl[rr*SROW_+cc] = s_raw[(size_t)(row0+rr)*SROW_+cc];
  }
  __syncthreads();
  int lr = t >> 4, ng = t & 15;
  for (int q=0;q<4;++q) {
    int n = ng + 16*q;
    float sp[16];
    #pragma unroll
    for (int p=0;p<16;++p) sp[p] = sl[lr*SROW_ + n*8 + p];
    float s1=0.f, s2=0.f;
    #pragma unroll
    for (int hid=0; hid<32; ++hid) {
      float acc = fc1_b[hid];
      #pragma unroll
      for (int p=0;p<16;++p) acc = fmaf(sp[p], fc1_w[hid*16+p], acc);
      float gv = gelu_f(acc);
      s1 += gv; s2 = fmaf(gv,gv,s2);
    }
    red[0][lr*64+n] = s1;
    red[1][lr*64+n] = s2;
  }
  __syncthreads();
  if (t < 64) {
    float S1=0.f, S2=0.f;
    for (int lr2=0; lr2<GR_; ++lr2) { S1 += red[0][lr2*64+t]; S2 += red[1][lr2*64+t]; }
    partials[((size_t)blockIdx.x*64+t)*2+0] = S1;
    partials[((size_t)blockIdx.x*64+t)*2+1] = S2;
  }
}

// ---------- K2v5: fc1 via OPERAND-SWAPPED MFMA (D = fc1·sp^T) ----------
// Output layout: patch in lane dim (fr), hid in reg dim (fg*4+reg) -> each lane
// holds 4 contiguous hids of ONE patch -> single ds_write_b64, conflict-free.
__global__ __launch_bounds__(512) void k2v5_bn1_cr(
    const float* __restrict__ s_raw,
    const float* __restrict__ fc1_w, const float* __restrict__ fc1_b,
    const float* __restrict__ conv_w,
    float* __restrict__ partials, __hip_bfloat16* __restrict__ crp) {
  __shared__ __align__(16) __hip_bfloat16 Hb[4*512*8];   // [hid>>3][patch][hid&7] 32 KB
  __shared__ float cw[192];
  __shared__ float red[2][512];
  int t = threadIdx.x;
  int row0 = blockIdx.x*8;
  if (t < 192) cw[t] = conv_w[t];
  int lane = t & 63, w = t >> 6;
  int fr = lane & 15, fg = lane >> 4;
  bf16x8 z8 = (bf16x8){0,0,0,0,0,0,0,0};
  bf16x8 wv0 = (fg < 2) ? cvt8(&fc1_w[(0*16+fr)*16 + fg*8]) : z8;
  bf16x8 wv1 = (fg < 2) ? cvt8(&fc1_w[(1*16+fr)*16 + fg*8]) : z8;
  f32x4 acc[4][2];
  #pragma unroll
  for (int mt=0;mt<4;++mt)
    #pragma unroll
    for (int nt=0;nt<2;++nt) acc[mt][nt] = (f32x4){0.f,0.f,0.f,0.f};
  #pragma unroll
  for (int mt=0;mt<4;++mt) {
    int p = (w*4+mt)*16 + fr;
    int lr = p>>6, n = p&63;
    bf16x8 pv = (fg < 2) ? cvt8(&s_raw[(size_t)(row0+lr)*SROW_ + n*8 + fg*8]) : z8;
    acc[mt][0] = __builtin_amdgcn_mfma_f32_16x16x32_bf16(wv0, pv, acc[mt][0], 0,0,0);
    acc[mt][1] = __builtin_amdgcn_mfma_f32_16x16x32_bf16(wv1, pv, acc[mt][1], 0,0,0);
  }
  #pragma unroll
  for (int mt=0;mt<4;++mt) {
    int p = (w*4+mt)*16 + fr;
    #pragma unroll
    for (int nt=0;nt<2;++nt) {
      float4 b4 = ((const float4*)fc1_b)[nt*4+fg];
      float g0 = gelu_f(acc[mt][nt][0] + b4.x);
      float g1 = gelu_f(acc[mt][nt][1] + b4.y);
      float g2 = gelu_f(acc[mt][nt][2] + b4.z);
      float g3 = gelu_f(acc[mt][nt][3] + b4.w);
      unsigned lo = (unsigned)bf16bits(g0) | (((unsigned)bf16bits(g1))<<16);
      unsigned hi = (unsigned)bf16bits(g2) | (((unsigned)bf16bits(g3))<<16);
      int hb = nt*16 + fg*4;
      *(uint2*)&Hb[(hb>>3)*4096 + p*8 + (hb&7)] = make_uint2(lo, hi);
    }
  }
  __syncthreads();
  {
    int n = t & 63;
    uint4 u0 = *(const uint4*)&Hb[0*4096 + t*8];
    uint4 u1 = *(const uint4*)&Hb[1*4096 + t*8];
    uint4 u2 = *(const uint4*)&Hb[2*4096 + t*8];
    uint4 u3 = *(const uint4*)&Hb[3*4096 + t*8];
    unsigned uw[16] = {u0.x,u0.y,u0.z,u0.w, u1.x,u1.y,u1.z,u1.w,
                       u2.x,u2.y,u2.z,u2.w, u3.x,u3.y,u3.z,u3.w};
    float g[32];
    #pragma unroll
    for (int j=0;j<16;++j) {
      g[2*j]   = __uint_as_float(uw[j]<<16);
      g[2*j+1] = __uint_as_float(uw[j] & 0xffff0000u);
    }
    float s1=0.f, s2=0.f;
    #pragma unroll
    for (int k=0;k<32;++k) { s1 += g[k]; s2 = fmaf(g[k], g[k], s2); }
    float w0=cw[n*3], wm=cw[n*3+1], wp=cw[n*3+2];
    unsigned wds[16]; unsigned crlo = 0;
    float prevv = 0.f;
    #pragma unroll
    for (int k=0;k<32;++k) {
      float cr = fmaf(prevv, w0, fmaf(g[k], wm, (k<31) ? g[k+1]*wp : 0.f));
      prevv = g[k];
      unsigned hbits = bf16bits(cr);
      if ((k&1)==0) crlo = hbits; else wds[k>>1] = crlo | (hbits<<16);
    }
    uint4* dst = (uint4*)&crp[((size_t)row0*64 + t)*32];
    dst[0] = make_uint4(wds[0],wds[1],wds[2],wds[3]);
    dst[1] = make_uint4(wds[4],wds[5],wds[6],wds[7]);
    dst[2] = make_uint4(wds[8],wds[9],wds[10],wds[11]);
    dst[3] = make_uint4(wds[12],wds[13],wds[14],wds[15]);
    red[0][t] = s1;
    red[1][t] = s2;
  }
  __syncthreads();
  if (t < 64) {
    float S1=0.f, S2=0.f;
    #pragma unroll
    for (int lr2=0; lr2<8; ++lr2) { S1 += red[0][lr2*64+t]; S2 += red[1][lr2*64+t]; }
    partials[((size_t)blockIdx.x*64+t)*2+0] = S1;
    partials[((size_t)blockIdx.x*64+t)*2+1] = S2;
  }
}

// ---------- bn reduce ----------
__global__ __launch_bounds__(256) void k_bnreduce(
    const float* __restrict__ partials, int nblk,
    const float* __restrict__ bnw, const float* __restrict__ bnb,
    float* __restrict__ scale, float* __restrict__ shift) {
  __shared__ float red[2][256];
  int n = blockIdx.x, t = threadIdx.x;
  float s1=0.f, s2=0.f;
  for (int i=t; i<nblk; i+=256) {
    s1 += partials[((size_t)i*64+n)*2+0];
    s2 += partials[((size_t)i*64+n)*2+1];
  }
  red[0][t]=s1; red[1][t]=s2;
  __syncthreads();
  for (int off=128; off>0; off>>=1) {
    if (t<off) { red[0][t]+=red[0][t+off]; red[1][t]+=red[1][t+off]; }
    __syncthreads();
  }
  if (t==0) {
    const float count = (float)BC_ * 32.0f;
    float mu = red[0][0]/count;
    float var = red[1][0]/count - mu*mu;
    float sc = rsqrtf(var + EPS_) * bnw[n];
    scale[n] = sc;
    shift[n] = bnb[n] - mu*sc;
  }
}

// ---------- K3 (fallback): BN2 statistics ----------
__global__ __launch_bounds__(256) void k3_bn2stats(
    const float* __restrict__ s_raw,
    const float* __restrict__ fc1_w, const float* __restrict__ fc1_b,
    const float* __restrict__ scale1, const float* __restrict__ shift1,
    const float* __restrict__ conv_w, const float* __restrict__ conv_b,
    float* __restrict__ partials) {
  __shared__ float sl[GR_*SROW_];
  __shared__ float sc1[64], sh1[64], cw[192], cb[64];
  __shared__ float red[2][GR_*64];
  int t = threadIdx.x;
  int row0 = blockIdx.x*GR_;
  if (t < 64) { sc1[t]=scale1[t]; sh1[t]=shift1[t]; cb[t]=conv_b[t]; }
  if (t >= 64 && t < 256) cw[t-64] = conv_w[t-64];
  __syncthreads();
  for (int idx=t; idx<GR_*520; idx+=256) {
    int rr = idx/520, cc = idx - rr*520;
    sl[rr*SROW_+cc] = s_raw[(size_t)(row0+rr)*SROW_+cc];
  }
  __syncthreads();
  int lr = t >> 4, ng = t & 15;
  for (int q=0;q<4;++q) {
    int n = ng + 16*q;
    float sp[16];
    #pragma unroll
    for (int p=0;p<16;++p) sp[p] = sl[lr*SROW_ + n*8 + p];
    float scn = sc1[n], shn = sh1[n];
    float h[32];
    #pragma unroll
    for (int hid=0; hid<32; ++hid) {
      float acc = fc1_b[hid];
      #pragma unroll
      for (int p=0;p<16;++p) acc = fmaf(sp[p], fc1_w[hid*16+p], acc);
      h[hid] = fmaf(gelu_f(acc), scn, shn);
    }
    float w0=cw[n*3], wm=cw[n*3+1], wpp=cw[n*3+2], cbn=cb[n];
    float s1=0.f, s2=0.f, prev=0.f;
    #pragma unroll
    for (int k2=0;k2<32;++k2) {
      float cur = h[k2];
      float cv = cbn;
      cv = fmaf(prev, w0, cv);
      cv = fmaf(cur, wm, cv);
      if (k2<31) cv = fmaf(h[k2+1], wpp, cv);
      float gv = gelu_f(cv);
      s1 += gv; s2 = fmaf(gv,gv,s2);
      prev = cur;
    }
    red[0][lr*64+n]=s1; red[1][lr*64+n]=s2;
  }
  __syncthreads();
  if (t < 64) {
    float S1=0.f, S2=0.f;
    for (int lr2=0; lr2<GR_; ++lr2) { S1 += red[0][lr2*64+t]; S2 += red[1][lr2*64+t]; }
    partials[((size_t)blockIdx.x*64+t)*2+0] = S1;
    partials[((size_t)blockIdx.x*64+t)*2+1] = S2;
  }
}

// ---------- K3v3: BN2 stats + fused fc2 partial (U = fc2_w · g2), U in fp16 ----------
// U is independent of bn2 affine (per-n scale uniform over k). crp is read-only.
__global__ __launch_bounds__(512) void k3v3_bn2_u(
    const __hip_bfloat16* __restrict__ crp,
    const float* __restrict__ scale1, const float* __restrict__ shift1,
    const float* __restrict__ conv_w, const float* __restrict__ conv_b,
    const float* __restrict__ fc2_w,
    float* __restrict__ partials, __half* __restrict__ Ub) {
  __shared__ float sc1[64], sh0l[64], shml[64], sh31l[64];
  __shared__ float red[2][512];
  int t = threadIdx.x;
  int row0 = blockIdx.x*8;
  if (t < 64) {
    float w0=conv_w[t*3], wm=conv_w[t*3+1], wp=conv_w[t*3+2];
    float s1v=shift1[t], cbv=conv_b[t];
    sc1[t]  = scale1[t];
    sh0l[t] = fmaf(s1v, wm+wp, cbv);
    shml[t] = fmaf(s1v, w0+wm+wp, cbv);
    sh31l[t]= fmaf(s1v, w0+wm, cbv);
  }
  __syncthreads();
  int n = t&63;
  const uint4* crb = (const uint4*)&crp[((size_t)row0*64 + t)*32];
  uint4 u0=crb[0], u1=crb[1], u2=crb[2], u3=crb[3];
  unsigned uw[16] = {u0.x,u0.y,u0.z,u0.w, u1.x,u1.y,u1.z,u1.w,
                     u2.x,u2.y,u2.z,u2.w, u3.x,u3.y,u3.z,u3.w};
  float sc1n = sc1[n];
  float shm = shml[n];
  float g[32];
  float s1=0.f, s2=0.f;
  #pragma unroll
  for (int j=0;j<16;++j) {
    unsigned u = uw[j];
    float c0 = __uint_as_float(u<<16);
    float c1 = __uint_as_float(u & 0xffff0000u);
    float sh_0 = (j==0)  ? sh0l[n]  : shm;
    float sh_1 = (j==15) ? sh31l[n] : shm;
    float g0 = gelu_f(fmaf(c0, sc1n, sh_0));
    float g1 = gelu_f(fmaf(c1, sc1n, sh_1));
    g[2*j]   = g0;
    g[2*j+1] = g1;
    s1 += g0 + g1;
    s2 = fmaf(g0,g0, fmaf(g1,g1, s2));
  }
  // U[p'] = sum_k fc2_w[p'][k] * g[k]   (fc2_w uniform -> scalar loads)
  unsigned wds[8];
  #pragma unroll
  for (int jj=0;jj<8;++jj) {
    float ua = 0.f, ub = 0.f;
    #pragma unroll
    for (int k=0;k<32;++k) {
      ua = fmaf(fc2_w[(2*jj  )*32+k], g[k], ua);
      ub = fmaf(fc2_w[(2*jj+1)*32+k], g[k], ub);
    }
    wds[jj] = (unsigned)f16bits(ua) | (((unsigned)f16bits(ub))<<16);
  }
  uint4* dst = (uint4*)&Ub[((size_t)row0*64 + t)*16];
  dst[0] = make_uint4(wds[0],wds[1],wds[2],wds[3]);
  dst[1] = make_uint4(wds[4],wds[5],wds[6],wds[7]);
  red[0][t]=s1; red[1][t]=s2;
  __syncthreads();
  if (t < 64) {
    float S1=0.f, S2=0.f;
    #pragma unroll
    for (int lr2=0; lr2<8; ++lr2) { S1 += red[0][lr2*64+t]; S2 += red[1][lr2*64+t]; }
    partials[((size_t)blockIdx.x*64+t)*2+0] = S1;
    partials[((size_t)blockIdx.x*64+t)*2+1] = S2;
  }
}

// ---------- K5a (fallback): full per-row pipeline ----------
__global__ __launch_bounds__(256) void k5a_pipeline(
    const float* __restrict__ s_raw, const float* __restrict__ wl_g,
    const float* __restrict__ fc1_w, const float* __restrict__ fc1_b,
    const float* __restrict__ scale1, const float* __restrict__ shift1,
    const float* __restrict__ conv_w, const float* __restrict__ conv_b,
    const float* __restrict__ scale2, const float* __restrict__ shift2,
    const float* __restrict__ fc2_w, const float* __restrict__ fc2_b,
    const float* __restrict__ gl_scale,
    const float* __restrict__ ln_w, const float* __restrict__ ln_b,
    __hip_bfloat16* __restrict__ ybf) {
  __shared__ float sl[RB_*SROW_];
  __shared__ float cw[192], cb[64];
  __shared__ float sc1[64], sh1[64], sc2[64], sh2[64];
  int t = threadIdx.x;
  int row0 = blockIdx.x*RB_;
  if (t<64) { sc1[t]=scale1[t]; sh1[t]=shift1[t]; sc2[t]=scale2[t]; sh2[t]=shift2[t]; cb[t]=conv_b[t]; }
  if (t>=64 && t<256) cw[t-64]=conv_w[t-64];
  __syncthreads();
  for (int idx=t; idx<RB_*520; idx+=256) {
    int rr = idx/520, cc = idx - rr*520;
    sl[rr*SROW_+cc] = s_raw[(size_t)(row0+rr)*SROW_+cc];
  }
  __syncthreads();
  float glv = gl_scale[0];
  for (int idx=t; idx<RB_*64; idx+=256) {
    int rr = idx>>6, n = idx&63;
    float wlv = wl_g[(size_t)row0*64 + idx];
    float h[32];
    {
      float sp[16];
      #pragma unroll
      for (int p=0;p<16;++p) sp[p] = sl[rr*SROW_ + n*8 + p];
      float scn=sc1[n], shn=sh1[n];
      #pragma unroll
      for (int hid=0;hid<32;++hid) {
        float acc=fc1_b[hid];
        #pragma unroll
        for (int p=0;p<16;++p) acc=fmaf(sp[p], fc1_w[hid*16+p], acc);
        h[hid]=fmaf(gelu_f(acc), scn, shn);
      }
    }
    {
      float w0=cw[n*3], wm=cw[n*3+1], wpp=cw[n*3+2], cbn=cb[n];
      float sc2n=sc2[n], sh2n=sh2[n];
      float prev=0.f;
      #pragma unroll
      for (int k2=0;k2<32;++k2) {
        float cur = h[k2];
        float cv = cbn;
        cv = fmaf(prev, w0, cv);
        cv = fmaf(cur, wm, cv);
        if (k2<31) cv = fmaf(h[k2+1], wpp, cv);
        h[k2] = fmaf(gelu_f(cv), sc2n, sh2n);
        prev = cur;
      }
    }
    float yv[16];
    #pragma unroll
    for (int p=0;p<16;++p) {
      float acc=fc2_b[p];
      #pragma unroll
      for (int hid=0;hid<32;++hid) acc=fmaf(h[hid], fc2_w[p*32+hid], acc);
      yv[p]=acc;
    }
    float smul = 3.0f + glv*wlv;
    float mu=0.f;
    #pragma unroll
    for (int p=0;p<16;++p) {
      yv[p]=fmaf(sl[rr*SROW_ + n*8 + p], smul, yv[p]);
      mu+=yv[p];
    }
    mu *= (1.0f/16.0f);
    float var=0.f;
    #pragma unroll
    for (int p=0;p<16;++p){ float d=yv[p]-mu; var=fmaf(d,d,var); }
    var *= (1.0f/16.0f);
    float rs = rsqrtf(var + EPS_);
    unsigned int wds[8];
    #pragma unroll
    for (int j=0;j<8;++j) {
      unsigned int lo = bf16bits(fmaf((yv[2*j]-mu)*rs,   ln_w[2*j],   ln_b[2*j]));
      unsigned int hi = bf16bits(fmaf((yv[2*j+1]-mu)*rs, ln_w[2*j+1], ln_b[2*j+1]));
      wds[j] = lo | (hi<<16);
    }
    size_t ybase = (size_t)(row0+rr)*1024 + n*16;
    uint4* dst = (uint4*)&ybf[ybase];
    dst[0] = make_uint4(wds[0],wds[1],wds[2],wds[3]);
    dst[1] = make_uint4(wds[4],wds[5],wds[6],wds[7]);
  }
}

// ---------- K5a_v4: read U (fp16, aliased in ybf region), apply bn2 affine via
// linearity, residual + LN, overwrite same 32B with y (per-thread in-place) ----------
__global__ __launch_bounds__(512) void k5a_v4(
    const float* __restrict__ s_raw, const float* __restrict__ wl_g,
    const float* __restrict__ scale2, const float* __restrict__ shift2,
    const float* __restrict__ Wsum, const float* __restrict__ fc2_b,
    const float* __restrict__ gl_scale,
    const float* __restrict__ ln_w, const float* __restrict__ ln_b,
    __hip_bfloat16* __restrict__ ybf) {
  __shared__ float sc2l[64], sh2l[64];
  int t = threadIdx.x;
  int row0 = blockIdx.x*RB_;
  if (t < 64) { sc2l[t]=scale2[t]; sh2l[t]=shift2[t]; }
  __syncthreads();
  int rr = t>>6, n = t&63;
  int row = row0 + rr;
  float glv = gl_scale[0];
  float wlv = wl_g[(size_t)row*64 + n];
  size_t pbase = ((size_t)row*64 + n)*16;
  uint4* uptr = (uint4*)&ybf[pbase];
  uint4 a = uptr[0], b = uptr[1];
  unsigned hw[8] = {a.x,a.y,a.z,a.w, b.x,b.y,b.z,b.w};
  float sc2n = sc2l[n], sh2n = sh2l[n];
  float yv[16];
  #pragma unroll
  for (int j=0;j<8;++j) {
    float U0 = f16val((unsigned short)(hw[j] & 0xffffu));
    float U1 = f16val((unsigned short)(hw[j] >> 16));
    yv[2*j]   = fmaf(sc2n, U0, fmaf(sh2n, Wsum[2*j],   fc2_b[2*j]));
    yv[2*j+1] = fmaf(sc2n, U1, fmaf(sh2n, Wsum[2*j+1], fc2_b[2*j+1]));
  }
  const float* sp_g = &s_raw[(size_t)row*SROW_ + n*8];
  float4 s0 = *(const float4*)(sp_g);
  float4 s1v = *(const float4*)(sp_g+4);
  float4 s2v = *(const float4*)(sp_g+8);
  float4 s3 = *(const float4*)(sp_g+12);
  float sp[16] = {s0.x,s0.y,s0.z,s0.w, s1v.x,s1v.y,s1v.z,s1v.w,
                  s2v.x,s2v.y,s2v.z,s2v.w, s3.x,s3.y,s3.z,s3.w};
  float smul = 3.0f + glv*wlv;
  float mu=0.f;
  #pragma unroll
  for (int p=0;p<16;++p) {
    yv[p] = fmaf(sp[p], smul, yv[p]);
    mu += yv[p];
  }
  mu *= (1.0f/16.0f);
  float var=0.f;
  #pragma unroll
  for (int p=0;p<16;++p){ float d=yv[p]-mu; var=fmaf(d,d,var); }
  var *= (1.0f/16.0f);
  float rs = rsqrtf(var + EPS_);
  unsigned int wds[8];
  #pragma unroll
  for (int j=0;j<8;++j) {
    unsigned int lo = bf16bits(fmaf((yv[2*j]-mu)*rs,   ln_w[2*j],   ln_b[2*j]));
    unsigned int hi = bf16bits(fmaf((yv[2*j+1]-mu)*rs, ln_w[2*j+1], ln_b[2*j+1]));
    wds[j] = lo | (hi<<16);
  }
  uptr[0] = make_uint4(wds[0],wds[1],wds[2],wds[3]);
  uptr[1] = make_uint4(wds[4],wds[5],wds[6],wds[7]);
}

// ---------- K5b: M=16 rows/block, 6 waves x 16 cols, LDS-staged (coalesced), 1-step reg prefetch ----------
__global__ __launch_bounds__(384) void k5b_gemm(
    const __hip_bfloat16* __restrict__ ybf, const __hip_bfloat16* __restrict__ tbf,
    const __hip_bfloat16* __restrict__ Wsf, const __hip_bfloat16* __restrict__ Wtf,
    const float* __restrict__ rowpar, const float* __restrict__ rev_b,
    const float* __restrict__ biasc, const float* __restrict__ colsumT,
    float* __restrict__ out) {
  __shared__ __align__(16) __hip_bfloat16 As[2*16*72];
  __shared__ __align__(16) __hip_bfloat16 Bs[2*96*72];
  __shared__ float rp[64];
  __shared__ float rbl[16];
  __shared__ int   obase[16];
  __shared__ float bcl[96], csl[96];
  int tid = threadIdx.x;
  int row0 = blockIdx.x*16;
  if (tid < 64) rp[tid] = rowpar[(size_t)row0*4 + tid];
  if (tid >= 64 && tid < 80) {
    int lr = tid-64;
    int row = row0 + lr; int b = row/C_; int c = row - b*C_;
    rbl[lr] = rev_b[c]; obase[lr] = b*PRED_*C_ + c;
  }
  if (tid >= 96 && tid < 192) { bcl[tid-96]=biasc[tid-96]; csl[tid-96]=colsumT[tid-96]; }
  int lane = tid & 63, w = tid >> 6;
  int fr = lane & 15, fg = lane >> 4;
  bool a0 = tid < 128;
  int r0 = a0 ? (tid>>3) : ((tid-128)>>3);
  int c0 = a0 ? (tid&7)  : ((tid-128)&7);
  int r1 = (tid+256)>>3, c1 = (tid+256)&7;
  bool h2 = tid < 128;
  int r2 = (tid+640)>>3, c2 = (tid+640)&7;
  f32x4 acc = (f32x4){0.f,0.f,0.f,0.f};

  uint4 v0, v1, v2;
  auto LOAD = [&](int ks){
    const __hip_bfloat16* Ag; const __hip_bfloat16* Bg; int K; int kofs;
    if (ks < 8) { Ag = tbf + (size_t)row0*512;  Bg = Wtf; K = 512;  kofs = ks*64; }
    else        { Ag = ybf + (size_t)row0*1024; Bg = Wsf; K = 1024; kofs = (ks-8)*64; }
    v0 = a0 ? *(const uint4*)(Ag + (size_t)r0*K + kofs + c0*8)
            : *(const uint4*)(Bg + (size_t)r0*K + kofs + c0*8);
    v1 = *(const uint4*)(Bg + (size_t)r1*K + kofs + c1*8);
    if (h2) v2 = *(const uint4*)(Bg + (size_t)r2*K + kofs + c2*8);
  };

  LOAD(0);
  int cur = 0;
  for (int ks=0; ks<24; ++ks) {
    __hip_bfloat16* Ab = &As[cur*16*72];
    __hip_bfloat16* Bb = &Bs[cur*96*72];
    if (a0) *(uint4*)&Ab[r0*72 + c0*8] = v0;
    else    *(uint4*)&Bb[r0*72 + c0*8] = v0;
    *(uint4*)&Bb[r1*72 + c1*8] = v1;
    if (h2) *(uint4*)&Bb[r2*72 + c2*8] = v2;
    __syncthreads();
    if (ks < 23) LOAD(ks+1);
    #pragma unroll
    for (int ksub=0; ksub<2; ++ksub) {
      bf16x8 av = *(bf16x8*)&Ab[fr*72 + ksub*32 + fg*8];
      bf16x8 bv = *(bf16x8*)&Bb[(w*16+fr)*72 + ksub*32 + fg*8];
      acc = __builtin_amdgcn_mfma_f32_16x16x32_bf16(av, bv, acc, 0,0,0);
    }
    cur ^= 1;
  }
  {
    int col = w*16 + fr;
    float cs = csl[col], bc = bcl[col];
    #pragma unroll
    for (int reg=0;reg<4;++reg) {
      int rloc = fg*4 + reg;
      float g = rp[rloc*4+1], meanv = rp[rloc*4+2], inva = rp[rloc*4+3];
      float val = acc[reg] + g*cs + bc;
      val = (val - rbl[rloc])*inva + meanv;
      out[(size_t)obase[rloc] + (size_t)col*C_] = val;
    }
  }
}

extern "C" void kernel_launch(void* const* d_in, const int* in_sizes, int n_in,
                              void* d_out, int out_size, void* d_ws, size_t ws_size,
                              hipStream_t stream) {
  const float* x      = (const float*)d_in[0];
  const float* rev_w  = (const float*)d_in[1];
  const float* rev_b  = (const float*)d_in[2];
  const float* fc1_w  = (const float*)d_in[3];
  const float* fc1_b  = (const float*)d_in[4];
  const float* bn1_w  = (const float*)d_in[5];
  const float* bn1_b  = (const float*)d_in[6];
  const float* conv_w = (const float*)d_in[7];
  const float* conv_b = (const float*)d_in[8];
  const float* bn2_w  = (const float*)d_in[9];
  const float* bn2_b  = (const float*)d_in[10];
  const float* fc2_w  = (const float*)d_in[11];
  const float* fc2_b  = (const float*)d_in[12];
  const float* m1_w   = (const float*)d_in[13];
  const float* m1_b   = (const float*)d_in[14];
  const float* m2_w   = (const float*)d_in[15];
  const float* m2_b   = (const float*)d_in[16];
  const float* gl     = (const float*)d_in[17];
  const float* ln_w   = (const float*)d_in[18];
  const float* ln_b   = (const float*)d_in[19];
  const float* seas_w = (const float*)d_in[20];
  const float* seas_b = (const float*)d_in[21];
  const float* tr_w   = (const float*)d_in[22];
  const float* tr_b   = (const float*)d_in[23];
  const float* fus_w  = (const float*)d_in[24];
  const float* fus_b  = (const float*)d_in[25];
  float* out = (float*)d_out;
  float* ws = (float*)d_ws;

  __hip_bfloat16* Wsf  = (__hip_bfloat16*)(ws);
  __hip_bfloat16* Wtf  = (__hip_bfloat16*)(ws + 49152);
  float* biasc   = ws + 73728;
  float* colsumT = ws + 73856;
  float* scale1  = ws + 73984;
  float* shift1  = ws + 74048;
  float* scale2  = ws + 74112;
  float* shift2  = ws + 74176;
  float* partials= ws + 74240;     // fallback partials; big path: first 16 floats = Wsum
  float* Wsum    = ws + 74240;
  float* rowpar  = ws + 238592;
  float* s_raw   = ws + 320768;
  __hip_bfloat16* t_bf = (__hip_bfloat16*)(ws + 11168000);
  __hip_bfloat16* ybf  = (__hip_bfloat16*)(ws + 16427264);
  float* pooled  = ws + 26945792;
  float* wl_g    = ws + 28260608;
  __hip_bfloat16* crp  = (__hip_bfloat16*)(ws + 29575424);  // BC*2048 bf16
  float* ppool   = ws + 26945792;   // big-path partials alias pooled (dead after k4)
  __half* Uh     = (__half*)ybf;    // U aliases ybf region (same per-patch 32B slots)
  const size_t NEED = (29575424ull + 21037056ull) * 4ull;   // ~202.5 MB (unchanged)
  bool big = (ws_size >= NEED);

  hipLaunchKernelGGL(k1_all, dim3(BC_/32 + 577), dim3(256), 0, stream,
    x, rev_w, rev_b, seas_w, tr_w, fus_w, seas_b, tr_b, fus_b, fc2_w,
    s_raw, t_bf, rowpar, pooled, Wsf, Wtf, biasc, colsumT, Wsum);
  hipLaunchKernelGGL(k4_gate, dim3(BC_/64), dim3(512), 0, stream, pooled, m1_w, m1_b, m2_w, m2_b, wl_g);
  if (big) {
    hipLaunchKernelGGL(k2v5_bn1_cr, dim3(NBLKH_), dim3(512), 0, stream, s_raw, fc1_w, fc1_b, conv_w, ppool, crp);
    hipLaunchKernelGGL(k_bnreduce, dim3(64), dim3(256), 0, stream, ppool, NBLKH_, bn1_w, bn1_b, scale1, shift1);
    hipLaunchKernelGGL(k3v3_bn2_u, dim3(NBLKH_), dim3(512), 0, stream, crp, scale1, shift1, conv_w, conv_b, fc2_w, ppool, Uh);
    hipLaunchKernelGGL(k_bnreduce, dim3(64), dim3(256), 0, stream, ppool, NBLKH_, bn2_w, bn2_b, scale2, shift2);
    hipLaunchKernelGGL(k5a_v4, dim3(NBLKH_), dim3(512), 0, stream,
      s_raw, wl_g, scale2, shift2, Wsum, fc2_b, gl, ln_w, ln_b, ybf);
  } else {
    hipLaunchKernelGGL(k2_bn1stats, dim3(NBLK2_), dim3(256), 0, stream, s_raw, fc1_w, fc1_b, partials);
    hipLaunchKernelGGL(k_bnreduce, dim3(64), dim3(256), 0, stream, partials, NBLK2_, bn1_w, bn1_b, scale1, shift1);
    hipLaunchKernelGGL(k3_bn2stats, dim3(NBLK2_), dim3(256), 0, stream, s_raw, fc1_w, fc1_b, scale1, shift1, conv_w, conv_b, partials);
    hipLaunchKernelGGL(k_bnreduce, dim3(64), dim3(256), 0, stream, partials, NBLK2_, bn2_w, bn2_b, scale2, shift2);
    hipLaunchKernelGGL(k5a_pipeline, dim3(BC_/RB_), dim3(256), 0, stream,
      s_raw, wl_g, fc1_w, fc1_b, scale1, shift1, conv_w, conv_b,
      scale2, shift2, fc2_w, fc2_b, gl, ln_w, ln_b, ybf);
  }
  hipLaunchKernelGGL(k5b_gemm, dim3(BC_/16), dim3(384), 0, stream,
    ybf, t_bf, Wsf, Wtf, rowpar, rev_b, biasc, colsumT, out);
}